// Round 3
// baseline (351.150 us; speedup 1.0000x reference)
//
#include <hip/hip_runtime.h>
#include <cstdio>
#include <cstdint>

// GridSelfAttention: N=320 seq, C=128 ch, H=4 heads, D=32 head-dim.
// k0 prep -> k1 LN+proj GEMM (head-grouped layouts) -> k2 attention (barrier-free,
// online softmax, XCD-swizzled) -> k3 output GEMM.

#define NSEQ 320
#define CCH  128
#define NN   102400        // NSEQ*NSEQ
#define QK_SCALE 0.17677669529663687f   // 1/sqrt(32), folded into Wq
#define LN_EPS 1e-5f
#define NEG_BIG -1e9f

typedef __bf16 bf16x8 __attribute__((ext_vector_type(8)));
typedef float  f32x4  __attribute__((ext_vector_type(4)));

__device__ __forceinline__ unsigned short f2bf(float f) {
    unsigned int u = __float_as_uint(f);
    unsigned int r = (u + 0x7FFFu + ((u >> 16) & 1u)) >> 16;  // RNE
    return (unsigned short)r;
}
__device__ __forceinline__ float bf2f(unsigned short h) {
    return __uint_as_float(((unsigned int)h) << 16);
}

// ---------------- k0: weight prep ----------------
__global__ __launch_bounds__(256) void prep_kernel(
    const float* __restrict__ wq, const float* __restrict__ wk, const float* __restrict__ wv,
    const float* __restrict__ wg, const float* __restrict__ wpb, const float* __restrict__ wo,
    const int* __restrict__ pmask,
    unsigned short* __restrict__ wcat, unsigned short* __restrict__ woutb, int* __restrict__ maskT)
{
    int idx = blockIdx.x * 256 + threadIdx.x;
    if (idx < 576 * 128) {
        int n = idx >> 7, c = idx & 127;
        float v;
        if      (n < 128) v = wq[c * 128 + n] * QK_SCALE;
        else if (n < 256) v = wk[c * 128 + (n - 128)];
        else if (n < 384) v = wv[c * 128 + (n - 256)];
        else if (n < 512) v = wg[c * 128 + (n - 384)];
        else if (n < 516) v = wpb[c * 4 + (n - 512)];
        else              v = 0.f;
        wcat[idx] = f2bf(v);
    } else if (idx < 576 * 128 + 128 * 128) {
        int i = idx - 576 * 128;
        woutb[i] = f2bf(wo[i]);
    } else if (idx < 576 * 128 + 128 * 128 + NN) {
        int i = idx - (576 * 128 + 128 * 128);
        int b = i / NSEQ, k = i - b * NSEQ;
        maskT[i] = pmask[k * NSEQ + b];
    }
}

// ---------------- k1: LayerNorm + fused projection GEMM ----------------
// Outputs (head-grouped for k2):
//   qh/kh/gh[((b*4+h)*320 + row)*32 + d]  bf16   (gh = sigmoid applied)
//   vT[((b*4+h)*32 + d)*320 + key]        bf16   (pre-transposed V)
//   biasS in MFMA-C-fragment order (k2 C-operand, coalesced float4)
__global__ __launch_bounds__(256, 4) void ln_proj_kernel(
    const float* __restrict__ act, const float* __restrict__ gamma, const float* __restrict__ beta,
    const unsigned short* __restrict__ wcat,
    unsigned short* __restrict__ qh, unsigned short* __restrict__ kh, unsigned short* __restrict__ vT,
    unsigned short* __restrict__ gh, float* __restrict__ biasS)
{
    __shared__ __align__(16) float          fs[64 * 132];            // fp32 act stage, later aliased by B
    __shared__ __align__(16) unsigned short A_lds[64 * 136];         // LN(act) bf16; later fp32 scratch (17408 B)
    unsigned short* B_lds = (unsigned short*)fs;                     // alias

    const int tid  = threadIdx.x;
    const int row0 = blockIdx.x * 64;
    const int bidx = row0 / NSEQ;           // 320%64==0 -> tile never crosses b
    const int qoff = row0 % NSEQ;

    const float4* actv = (const float4*)(act + (size_t)row0 * 128);
    #pragma unroll
    for (int it = 0; it < 8; ++it) {
        int f = it * 256 + tid;
        int row = f >> 5, c4 = f & 31;
        float4 v = actv[f];
        *(float4*)&fs[row * 132 + c4 * 4] = v;
    }
    __syncthreads();

    {
        int row = tid >> 2, seg = tid & 3;
        const float* rp = &fs[row * 132 + seg * 32];
        float vals[32];
        float s = 0.f, sq = 0.f;
        #pragma unroll
        for (int i = 0; i < 32; ++i) { float v = rp[i]; vals[i] = v; s += v; sq += v * v; }
        s  += __shfl_xor(s, 1);  sq += __shfl_xor(sq, 1);
        s  += __shfl_xor(s, 2);  sq += __shfl_xor(sq, 2);
        float mean = s * (1.f / 128.f);
        float var  = sq * (1.f / 128.f) - mean * mean;
        float rstd = rsqrtf(var + LN_EPS);
        #pragma unroll
        for (int j = 0; j < 4; ++j) {
            int c0 = seg * 32 + j * 8;
            float4 g0 = *(const float4*)&gamma[c0];
            float4 g1 = *(const float4*)&gamma[c0 + 4];
            float4 b0 = *(const float4*)&beta[c0];
            float4 b1 = *(const float4*)&beta[c0 + 4];
            union { uint4 u; unsigned short us[8]; } pk;
            pk.us[0] = f2bf((vals[j*8+0] - mean) * rstd * g0.x + b0.x);
            pk.us[1] = f2bf((vals[j*8+1] - mean) * rstd * g0.y + b0.y);
            pk.us[2] = f2bf((vals[j*8+2] - mean) * rstd * g0.z + b0.z);
            pk.us[3] = f2bf((vals[j*8+3] - mean) * rstd * g0.w + b0.w);
            pk.us[4] = f2bf((vals[j*8+4] - mean) * rstd * g1.x + b1.x);
            pk.us[5] = f2bf((vals[j*8+5] - mean) * rstd * g1.y + b1.y);
            pk.us[6] = f2bf((vals[j*8+6] - mean) * rstd * g1.z + b1.z);
            pk.us[7] = f2bf((vals[j*8+7] - mean) * rstd * g1.w + b1.w);
            *(uint4*)&A_lds[row * 136 + c0] = pk.u;
        }
    }
    __syncthreads();

    const int wave = tid >> 6, lane = tid & 63, l15 = lane & 15, l4 = lane >> 4;
    bf16x8 afrag[4];
    #pragma unroll
    for (int kc = 0; kc < 4; ++kc)
        afrag[kc] = *(const bf16x8*)&A_lds[(wave * 16 + l15) * 136 + kc * 32 + l4 * 8];

    for (int nt = 0; nt < 9; ++nt) {
        // stage B chunk [64 n][128 k] bf16
        #pragma unroll
        for (int it = 0; it < 4; ++it) {
            int f = it * 256 + tid;
            int row = f >> 4, c16 = f & 15;
            uint4 u = *(const uint4*)&wcat[(nt * 64 + row) * 128 + c16 * 8];
            *(uint4*)&B_lds[row * 136 + c16 * 8] = u;
        }
        __syncthreads();   // B ready; also orders prev scratch reads before this iter's scratch writes

        f32x4 acc[4];
        #pragma unroll
        for (int ns = 0; ns < 4; ++ns) { f32x4 z = {0.f,0.f,0.f,0.f}; acc[ns] = z; }
        #pragma unroll
        for (int ns = 0; ns < 4; ++ns)
            #pragma unroll
            for (int kc = 0; kc < 4; ++kc) {
                bf16x8 bfrag = *(const bf16x8*)&B_lds[(ns * 16 + l15) * 136 + kc * 32 + l4 * 8];
                acc[ns] = __builtin_amdgcn_mfma_f32_16x16x32_bf16(afrag[kc], bfrag, acc[ns], 0, 0, 0);
            }

        if (nt == 4 || nt == 5) {
            // V: store directly from C-frags, pre-transposed (4 consecutive keys per lane)
            int key0 = qoff + wave * 16 + l4 * 4;
            #pragma unroll
            for (int ns = 0; ns < 4; ++ns) {
                int j  = nt * 64 + ns * 16 + l15 - 256;   // 0..255
                int hh = j >> 5, d = j & 31;
                ushort4 pk;
                pk.x = f2bf(acc[ns][0]); pk.y = f2bf(acc[ns][1]);
                pk.z = f2bf(acc[ns][2]); pk.w = f2bf(acc[ns][3]);
                *(ushort4*)&vT[((size_t)(bidx * 4 + hh) * 32 + d) * NSEQ + key0] = pk;
            }
            __syncthreads();   // protect B_lds before next staging
        } else if (nt == 8) {
            // bias -> swizzled C-fragment order
            #pragma unroll
            for (int ns = 0; ns < 4; ++ns) {
                int j = nt * 64 + ns * 16 + l15;
                if (j < 516) {
                    #pragma unroll
                    for (int reg = 0; reg < 4; ++reg) {
                        int r  = row0 + wave * 16 + l4 * 4 + reg;
                        int hh = j - 512;
                        int q  = r / NSEQ, key = r - q * NSEQ;
                        int qm = q & 15,  kl  = key & 15;
                        size_t a = (((size_t)(hh * 20 + (q >> 4)) * 20 + (key >> 4)) << 8)
                                 + ((qm >> 2) << 6) + (kl << 2) + (qm & 3);
                        biasS[a] = acc[ns][reg];
                    }
                }
            }
            // last iteration: no barrier needed
        } else {
            // q / k / gate: transpose C-frags through LDS scratch -> vectorized stores
            float* scratch = (float*)A_lds;   // 64 x 68 fp32 = 17408 B, exact fit
            #pragma unroll
            for (int ns = 0; ns < 4; ++ns)
                #pragma unroll
                for (int reg = 0; reg < 4; ++reg)
                    scratch[(wave * 16 + l4 * 4 + reg) * 68 + ns * 16 + l15] = acc[ns][reg];
            __syncthreads();

            int rrow = tid >> 2, c16 = tid & 3;
            int q = qoff + rrow;
            float f[16];
            #pragma unroll
            for (int i = 0; i < 4; ++i)
                *(float4*)&f[i * 4] = *(const float4*)&scratch[rrow * 68 + c16 * 16 + i * 4];

            int jbase = nt * 64 + c16 * 16;
            int cls   = jbase >> 7;            // 0=q, 1=k, 3=gate
            int jl    = jbase & 127;
            int hh = jl >> 5, d0 = jl & 31;
            unsigned short* dst = (cls == 0) ? qh : (cls == 1) ? kh : gh;
            if (cls == 3) {
                #pragma unroll
                for (int i = 0; i < 16; ++i) f[i] = 1.f / (1.f + __expf(-f[i]));
            }
            union { uint4 u[2]; unsigned short us[16]; } pk;
            #pragma unroll
            for (int i = 0; i < 16; ++i) pk.us[i] = f2bf(f[i]);
            size_t base = ((size_t)(bidx * 4 + hh) * NSEQ + q) * 32 + d0;
            *(uint4*)&dst[base]     = pk.u[0];
            *(uint4*)&dst[base + 8] = pk.u[1];
            // next loop iteration's post-staging barrier orders these reads vs next scratch writes
        }
    }
}

// ---------------- k2: attention ----------------
// block = (b, h, q-tile of 64), XCD-swizzled so the 5 qblk siblings of a (b,h)
// share an XCD L2. Barrier-free: all operands loaded in MFMA layout from global;
// only per-wave P double-buffer in LDS. Online softmax over 2 chunks of 160 keys.
__global__ __launch_bounds__(256, 6) void attn_kernel(
    const unsigned short* __restrict__ qh, const unsigned short* __restrict__ kh,
    const unsigned short* __restrict__ vT, const unsigned short* __restrict__ gh,
    const float* __restrict__ biasS, const int* __restrict__ maskT,
    unsigned short* __restrict__ waG)
{
    __shared__ __align__(16) unsigned short Pb[4][2][16 * 36];  // 9216 B

    const int tid  = threadIdx.x;
    const int bid  = blockIdx.x;
    const int xcd  = bid & 7;
    const int loc  = bid >> 3;
    const int qblk = loc % 5;
    const int g    = (loc / 5) * 8 + xcd;    // (b,h) group; siblings share xcd
    const int b    = g >> 2;
    const int h    = g & 3;
    const int wave = tid >> 6, lane = tid & 63, l15 = lane & 15, l4 = lane >> 4;

    const int qrow = qblk * 64 + wave * 16;
    const int qb16 = qblk * 4 + wave;
    const size_t hb  = (size_t)(b * 4 + h) * NSEQ;
    const size_t hbv = (size_t)(b * 4 + h) * 32;

    bf16x8 aQ = *(const bf16x8*)&qh[(hb + qrow + l15) * 32 + l4 * 8];
    const float* bsw = biasS + (size_t)(h * 20 + qb16) * 20 * 256 + lane * 4;
    const int*   mp  = maskT + b * NSEQ + l15;

    unsigned short* pb[2] = { Pb[wave][0], Pb[wave][1] };
    f32x4 acc[2];
    { f32x4 z = {0.f,0.f,0.f,0.f}; acc[0] = z; acc[1] = z; }
    float mrun[4], lrun[4];
    #pragma unroll
    for (int r = 0; r < 4; ++r) { mrun[r] = -3.4e38f; lrun[r] = 0.f; }

    #pragma unroll
    for (int ch = 0; ch < 2; ++ch) {
        const int t0 = ch * 10;
        f32x4 s[10];
        #pragma unroll
        for (int t = 0; t < 10; ++t) {
            f32x4 c = *(const f32x4*)&bsw[(t0 + t) * 256];
            bf16x8 bK = *(const bf16x8*)&kh[(hb + (t0 + t) * 16 + l15) * 32 + l4 * 8];
            s[t] = __builtin_amdgcn_mfma_f32_16x16x32_bf16(aQ, bK, c, 0, 0, 0);
        }
        #pragma unroll
        for (int t = 0; t < 10; ++t) {
            int m = mp[(t0 + t) * 16];
            #pragma unroll
            for (int r = 0; r < 4; ++r) s[t][r] = m ? s[t][r] : NEG_BIG;
        }
        float alpha[4];
        #pragma unroll
        for (int r = 0; r < 4; ++r) {
            float mx = -3.4e38f;
            #pragma unroll
            for (int t = 0; t < 10; ++t) mx = fmaxf(mx, s[t][r]);
            mx = fmaxf(mx, __shfl_xor(mx, 1));
            mx = fmaxf(mx, __shfl_xor(mx, 2));
            mx = fmaxf(mx, __shfl_xor(mx, 4));
            mx = fmaxf(mx, __shfl_xor(mx, 8));
            float mnew = fmaxf(mrun[r], mx);
            alpha[r] = __expf(mrun[r] - mnew);   // first chunk: exp(-huge)=0, lrun=0 anyway
            mrun[r]  = mnew;
            float l = 0.f;
            #pragma unroll
            for (int t = 0; t < 10; ++t) { float p = __expf(s[t][r] - mnew); s[t][r] = p; l += p; }
            l += __shfl_xor(l, 1); l += __shfl_xor(l, 2); l += __shfl_xor(l, 4); l += __shfl_xor(l, 8);
            lrun[r] = lrun[r] * alpha[r] + l;
        }
        #pragma unroll
        for (int ns = 0; ns < 2; ++ns)
            #pragma unroll
            for (int r = 0; r < 4; ++r)
                acc[ns][r] *= alpha[r];

        // stream unnormalized P through per-wave LDS dbuf (32 keys/sub-chunk); PV MFMA
        #pragma unroll
        for (int tt = 0; tt < 2; ++tt)
            #pragma unroll
            for (int r = 0; r < 4; ++r)
                pb[0][(l4 * 4 + r) * 36 + tt * 16 + l15] = f2bf(s[tt][r]);
        #pragma unroll
        for (int kc = 0; kc < 5; ++kc) {
            bf16x8 aW = *(const bf16x8*)&pb[kc & 1][l15 * 36 + l4 * 8];
            if (kc < 4) {
                unsigned short* nxt = pb[(kc + 1) & 1];
                #pragma unroll
                for (int tt = 0; tt < 2; ++tt)
                    #pragma unroll
                    for (int r = 0; r < 4; ++r)
                        nxt[(l4 * 4 + r) * 36 + tt * 16 + l15] = f2bf(s[2 * kc + 2 + tt][r]);
            }
            #pragma unroll
            for (int ns = 0; ns < 2; ++ns) {
                bf16x8 bV = *(const bf16x8*)&vT[(hbv + ns * 16 + l15) * NSEQ + ch * 160 + kc * 32 + l4 * 8];
                acc[ns] = __builtin_amdgcn_mfma_f32_16x16x32_bf16(aW, bV, acc[ns], 0, 0, 0);
            }
        }
    }

    // epilogue: normalize, * gate -> bf16
    #pragma unroll
    for (int r = 0; r < 4; ++r) lrun[r] = 1.f / lrun[r];
    #pragma unroll
    for (int ns = 0; ns < 2; ++ns)
        #pragma unroll
        for (int r = 0; r < 4; ++r) {
            int q   = qrow + l4 * 4 + r;
            int col = ns * 16 + l15;
            float gv = bf2f(gh[(hb + q) * 32 + col]);
            waG[((size_t)b * NSEQ + q) * 128 + h * 32 + col] = f2bf(acc[ns][r] * lrun[r] * gv);
        }
}

// ---------------- k3: output projection ----------------
__global__ __launch_bounds__(256, 4) void out_proj_kernel(
    const unsigned short* __restrict__ waG, const unsigned short* __restrict__ woutb,
    float* __restrict__ out)
{
    __shared__ __align__(16) unsigned short A_lds[64 * 136];
    __shared__ __align__(16) unsigned short B_lds[128 * 136];
    const int tid  = threadIdx.x;
    const int row0 = blockIdx.x * 64;

    #pragma unroll
    for (int it = 0; it < 4; ++it) {
        int f = it * 256 + tid;
        int row = f >> 4, c16 = f & 15;
        uint4 u = *(const uint4*)&waG[(size_t)(row0 + row) * 128 + c16 * 8];
        *(uint4*)&A_lds[row * 136 + c16 * 8] = u;
    }
    #pragma unroll
    for (int it = 0; it < 8; ++it) {
        int f = it * 256 + tid;
        int row = f >> 4, c16 = f & 15;
        uint4 u = *(const uint4*)&woutb[f * 8];
        *(uint4*)&B_lds[row * 136 + c16 * 8] = u;
    }
    __syncthreads();

    const int wave = tid >> 6, lane = tid & 63, l15 = lane & 15, l4 = lane >> 4;
    bf16x8 afrag[4];
    #pragma unroll
    for (int kc = 0; kc < 4; ++kc)
        afrag[kc] = *(const bf16x8*)&A_lds[(wave * 16 + l15) * 136 + kc * 32 + l4 * 8];
    f32x4 acc[8];
    #pragma unroll
    for (int ns = 0; ns < 8; ++ns) { f32x4 z = {0.f,0.f,0.f,0.f}; acc[ns] = z; }
    #pragma unroll
    for (int ns = 0; ns < 8; ++ns)
        #pragma unroll
        for (int kc = 0; kc < 4; ++kc) {
            bf16x8 bfrag = *(const bf16x8*)&B_lds[(ns * 16 + l15) * 136 + kc * 32 + l4 * 8];
            acc[ns] = __builtin_amdgcn_mfma_f32_16x16x32_bf16(afrag[kc], bfrag, acc[ns], 0, 0, 0);
        }
    #pragma unroll
    for (int ns = 0; ns < 8; ++ns)
        #pragma unroll
        for (int reg = 0; reg < 4; ++reg) {
            int r = row0 + wave * 16 + l4 * 4 + reg;
            out[(size_t)r * 128 + ns * 16 + l15] = acc[ns][reg];
        }
}

// ---------------- launch ----------------
extern "C" void kernel_launch(void* const* d_in, const int* in_sizes, int n_in,
                              void* d_out, int out_size, void* d_ws, size_t ws_size,
                              hipStream_t stream)
{
    (void)in_sizes; (void)n_in; (void)out_size;
    const float* act  = (const float*)d_in[0];
    const int*   pmsk = (const int*)d_in[1];
    const float* gam  = (const float*)d_in[2];
    const float* bet  = (const float*)d_in[3];
    const float* wpb  = (const float*)d_in[4];
    const float* wq   = (const float*)d_in[5];
    const float* wk   = (const float*)d_in[6];
    const float* wv   = (const float*)d_in[7];
    const float* wg   = (const float*)d_in[8];
    const float* wo   = (const float*)d_in[9];
    float* out = (float*)d_out;

    char* ws = (char*)d_ws;
    unsigned short* wcat  = (unsigned short*)(ws + 0);          //   147456 B
    unsigned short* woutb = (unsigned short*)(ws + 147456);     //    32768 B
    int*            maskT = (int*)           (ws + 180224);     //   409600 B
    float*          biasS = (float*)         (ws + 589824);     //  1638400 B (swizzled)
    unsigned short* qh    = (unsigned short*)(ws + 2228224);    // 26214400 B
    unsigned short* kh    = (unsigned short*)(ws + 28442624);
    unsigned short* vT    = (unsigned short*)(ws + 54657024);
    unsigned short* gh    = (unsigned short*)(ws + 80871424);
    unsigned short* wabuf = (unsigned short*)(ws + 107085824);  // ends 133300224
    if (ws_size < 133300224ull) {
        fprintf(stderr, "kernel_launch: ws too small (%zu < 133300224)\n", ws_size);
        return;
    }

    prep_kernel    <<<752,  256, 0, stream>>>(wq, wk, wv, wg, wpb, wo, pmsk, wcat, woutb, maskT);
    ln_proj_kernel <<<1600, 256, 0, stream>>>(act, gam, bet, wcat, qh, kh, vT, gh, biasS);
    attn_kernel    <<<6400, 256, 0, stream>>>(qh, kh, vT, gh, biasS, maskT, wabuf);
    out_proj_kernel<<<1600, 256, 0, stream>>>(wabuf, woutb, out);
}

// Round 4
// 265.556 us; speedup vs baseline: 1.3223x; 1.3223x over previous
//
#include <hip/hip_runtime.h>
#include <cstdio>
#include <cstdint>

// GridSelfAttention: N=320 seq, C=128 ch, H=4 heads, D=32 head-dim.
// k0 prep -> k1 LN+proj GEMM (head-grouped layouts) -> k2 attention (K in LDS,
// bias as MFMA-C, XCD-swizzled, head-major output) -> k3 output GEMM.

#define NSEQ 320
#define CCH  128
#define NN   102400        // NSEQ*NSEQ
#define QK_SCALE 0.17677669529663687f   // 1/sqrt(32), folded into Wq
#define LN_EPS 1e-5f
#define NEG_BIG -1e9f

typedef __bf16 bf16x8 __attribute__((ext_vector_type(8)));
typedef float  f32x4  __attribute__((ext_vector_type(4)));

__device__ __forceinline__ unsigned short f2bf(float f) {
    unsigned int u = __float_as_uint(f);
    unsigned int r = (u + 0x7FFFu + ((u >> 16) & 1u)) >> 16;  // RNE
    return (unsigned short)r;
}
__device__ __forceinline__ float bf2f(unsigned short h) {
    return __uint_as_float(((unsigned int)h) << 16);
}

// ---------------- k0: weight prep ----------------
__global__ __launch_bounds__(256) void prep_kernel(
    const float* __restrict__ wq, const float* __restrict__ wk, const float* __restrict__ wv,
    const float* __restrict__ wg, const float* __restrict__ wpb, const float* __restrict__ wo,
    const int* __restrict__ pmask,
    unsigned short* __restrict__ wcat, unsigned short* __restrict__ woutb, int* __restrict__ maskT)
{
    int idx = blockIdx.x * 256 + threadIdx.x;
    if (idx < 576 * 128) {
        int n = idx >> 7, c = idx & 127;
        float v;
        if      (n < 128) v = wq[c * 128 + n] * QK_SCALE;
        else if (n < 256) v = wk[c * 128 + (n - 128)];
        else if (n < 384) v = wv[c * 128 + (n - 256)];
        else if (n < 512) v = wg[c * 128 + (n - 384)];
        else if (n < 516) v = wpb[c * 4 + (n - 512)];
        else              v = 0.f;
        wcat[idx] = f2bf(v);
    } else if (idx < 576 * 128 + 128 * 128) {
        int i = idx - 576 * 128;
        woutb[i] = f2bf(wo[i]);
    } else if (idx < 576 * 128 + 128 * 128 + NN) {
        int i = idx - (576 * 128 + 128 * 128);
        int b = i / NSEQ, k = i - b * NSEQ;
        maskT[i] = pmask[k * NSEQ + b];
    }
}

// ---------------- k1: LayerNorm + fused projection GEMM ----------------
// Outputs (head-grouped for k2):
//   qh/kh/gh[((b*4+h)*320 + row)*32 + d]  bf16   (gh = sigmoid applied)
//   vT[((b*4+h)*32 + d)*320 + key]        bf16   (pre-transposed V)
//   biasS in MFMA-C-fragment order (k2 C-operand, coalesced float4)
__global__ __launch_bounds__(256, 4) void ln_proj_kernel(
    const float* __restrict__ act, const float* __restrict__ gamma, const float* __restrict__ beta,
    const unsigned short* __restrict__ wcat,
    unsigned short* __restrict__ qh, unsigned short* __restrict__ kh, unsigned short* __restrict__ vT,
    unsigned short* __restrict__ gh, float* __restrict__ biasS)
{
    __shared__ __align__(16) float          fs[64 * 132];            // fp32 act stage, later aliased by B
    __shared__ __align__(16) unsigned short A_lds[64 * 136];         // LN(act) bf16; later fp32 scratch (17408 B)
    unsigned short* B_lds = (unsigned short*)fs;                     // alias

    const int tid  = threadIdx.x;
    const int row0 = blockIdx.x * 64;
    const int bidx = row0 / NSEQ;           // 320%64==0 -> tile never crosses b
    const int qoff = row0 % NSEQ;

    const float4* actv = (const float4*)(act + (size_t)row0 * 128);
    #pragma unroll
    for (int it = 0; it < 8; ++it) {
        int f = it * 256 + tid;
        int row = f >> 5, c4 = f & 31;
        float4 v = actv[f];
        *(float4*)&fs[row * 132 + c4 * 4] = v;
    }
    __syncthreads();

    {
        int row = tid >> 2, seg = tid & 3;
        const float* rp = &fs[row * 132 + seg * 32];
        float vals[32];
        float s = 0.f, sq = 0.f;
        #pragma unroll
        for (int i = 0; i < 32; ++i) { float v = rp[i]; vals[i] = v; s += v; sq += v * v; }
        s  += __shfl_xor(s, 1);  sq += __shfl_xor(sq, 1);
        s  += __shfl_xor(s, 2);  sq += __shfl_xor(sq, 2);
        float mean = s * (1.f / 128.f);
        float var  = sq * (1.f / 128.f) - mean * mean;
        float rstd = rsqrtf(var + LN_EPS);
        #pragma unroll
        for (int j = 0; j < 4; ++j) {
            int c0 = seg * 32 + j * 8;
            float4 g0 = *(const float4*)&gamma[c0];
            float4 g1 = *(const float4*)&gamma[c0 + 4];
            float4 b0 = *(const float4*)&beta[c0];
            float4 b1 = *(const float4*)&beta[c0 + 4];
            union { uint4 u; unsigned short us[8]; } pk;
            pk.us[0] = f2bf((vals[j*8+0] - mean) * rstd * g0.x + b0.x);
            pk.us[1] = f2bf((vals[j*8+1] - mean) * rstd * g0.y + b0.y);
            pk.us[2] = f2bf((vals[j*8+2] - mean) * rstd * g0.z + b0.z);
            pk.us[3] = f2bf((vals[j*8+3] - mean) * rstd * g0.w + b0.w);
            pk.us[4] = f2bf((vals[j*8+4] - mean) * rstd * g1.x + b1.x);
            pk.us[5] = f2bf((vals[j*8+5] - mean) * rstd * g1.y + b1.y);
            pk.us[6] = f2bf((vals[j*8+6] - mean) * rstd * g1.z + b1.z);
            pk.us[7] = f2bf((vals[j*8+7] - mean) * rstd * g1.w + b1.w);
            *(uint4*)&A_lds[row * 136 + c0] = pk.u;
        }
    }
    __syncthreads();

    const int wave = tid >> 6, lane = tid & 63, l15 = lane & 15, l4 = lane >> 4;
    bf16x8 afrag[4];
    #pragma unroll
    for (int kc = 0; kc < 4; ++kc)
        afrag[kc] = *(const bf16x8*)&A_lds[(wave * 16 + l15) * 136 + kc * 32 + l4 * 8];

    for (int nt = 0; nt < 9; ++nt) {
        // stage B chunk [64 n][128 k] bf16
        #pragma unroll
        for (int it = 0; it < 4; ++it) {
            int f = it * 256 + tid;
            int row = f >> 4, c16 = f & 15;
            uint4 u = *(const uint4*)&wcat[(nt * 64 + row) * 128 + c16 * 8];
            *(uint4*)&B_lds[row * 136 + c16 * 8] = u;
        }
        __syncthreads();   // B ready; also orders prev scratch reads before this iter's scratch writes

        f32x4 acc[4];
        #pragma unroll
        for (int ns = 0; ns < 4; ++ns) { f32x4 z = {0.f,0.f,0.f,0.f}; acc[ns] = z; }
        #pragma unroll
        for (int ns = 0; ns < 4; ++ns)
            #pragma unroll
            for (int kc = 0; kc < 4; ++kc) {
                bf16x8 bfrag = *(const bf16x8*)&B_lds[(ns * 16 + l15) * 136 + kc * 32 + l4 * 8];
                acc[ns] = __builtin_amdgcn_mfma_f32_16x16x32_bf16(afrag[kc], bfrag, acc[ns], 0, 0, 0);
            }

        if (nt == 4 || nt == 5) {
            // V: store directly from C-frags, pre-transposed (4 consecutive keys per lane)
            int key0 = qoff + wave * 16 + l4 * 4;
            #pragma unroll
            for (int ns = 0; ns < 4; ++ns) {
                int j  = nt * 64 + ns * 16 + l15 - 256;   // 0..255
                int hh = j >> 5, d = j & 31;
                ushort4 pk;
                pk.x = f2bf(acc[ns][0]); pk.y = f2bf(acc[ns][1]);
                pk.z = f2bf(acc[ns][2]); pk.w = f2bf(acc[ns][3]);
                *(ushort4*)&vT[((size_t)(bidx * 4 + hh) * 32 + d) * NSEQ + key0] = pk;
            }
            __syncthreads();   // protect B_lds before next staging
        } else if (nt == 8) {
            // bias -> swizzled C-fragment order
            #pragma unroll
            for (int ns = 0; ns < 4; ++ns) {
                int j = nt * 64 + ns * 16 + l15;
                if (j < 516) {
                    #pragma unroll
                    for (int reg = 0; reg < 4; ++reg) {
                        int r  = row0 + wave * 16 + l4 * 4 + reg;
                        int hh = j - 512;
                        int q  = r / NSEQ, key = r - q * NSEQ;
                        int qm = q & 15,  kl  = key & 15;
                        size_t a = (((size_t)(hh * 20 + (q >> 4)) * 20 + (key >> 4)) << 8)
                                 + ((qm >> 2) << 6) + (kl << 2) + (qm & 3);
                        biasS[a] = acc[ns][reg];
                    }
                }
            }
        } else {
            // q / k / gate: transpose C-frags through LDS scratch -> vectorized stores
            float* scratch = (float*)A_lds;   // 64 x 68 fp32 = 17408 B, exact fit
            #pragma unroll
            for (int ns = 0; ns < 4; ++ns)
                #pragma unroll
                for (int reg = 0; reg < 4; ++reg)
                    scratch[(wave * 16 + l4 * 4 + reg) * 68 + ns * 16 + l15] = acc[ns][reg];
            __syncthreads();

            int rrow = tid >> 2, c16 = tid & 3;
            int q = qoff + rrow;
            float f[16];
            #pragma unroll
            for (int i = 0; i < 4; ++i)
                *(float4*)&f[i * 4] = *(const float4*)&scratch[rrow * 68 + c16 * 16 + i * 4];

            int jbase = nt * 64 + c16 * 16;
            int cls   = jbase >> 7;            // 0=q, 1=k, 3=gate
            int jl    = jbase & 127;
            int hh = jl >> 5, d0 = jl & 31;
            unsigned short* dst = (cls == 0) ? qh : (cls == 1) ? kh : gh;
            if (cls == 3) {
                #pragma unroll
                for (int i = 0; i < 16; ++i) f[i] = 1.f / (1.f + __expf(-f[i]));
            }
            union { uint4 u[2]; unsigned short us[16]; } pk;
            #pragma unroll
            for (int i = 0; i < 16; ++i) pk.us[i] = f2bf(f[i]);
            size_t base = ((size_t)(bidx * 4 + hh) * NSEQ + q) * 32 + d0;
            *(uint4*)&dst[base]     = pk.u[0];
            *(uint4*)&dst[base + 8] = pk.u[1];
        }
    }
}

// ---------------- k2: attention ----------------
// block = (b, h, q-tile of 64), XCD-swizzled (5 qblk siblings share an XCD L2).
// K staged in LDS (padded stride 36, shared by 4 waves). Bias enters as MFMA C
// (all 20 loads in flight -> one latency exposure). V direct from global.
// Output head-major: block-contiguous full-line writes.
__global__ __launch_bounds__(256, 4) void attn_kernel(
    const unsigned short* __restrict__ qh, const unsigned short* __restrict__ kh,
    const unsigned short* __restrict__ vT, const unsigned short* __restrict__ gh,
    const float* __restrict__ biasS, const int* __restrict__ maskT,
    unsigned short* __restrict__ waG)
{
    __shared__ __align__(16) unsigned short Klds[320 * 36];     // 23040 B
    __shared__ __align__(16) unsigned short Pb[4][2][16 * 36];  //  9216 B

    const int tid  = threadIdx.x;
    const int bid  = blockIdx.x;
    const int xcd  = bid & 7;
    const int loc  = bid >> 3;
    const int qblk = loc % 5;
    const int g    = (loc / 5) * 8 + xcd;    // (b,h) group; siblings share xcd
    const int b    = g >> 2;
    const int h    = g & 3;
    const int wave = tid >> 6, lane = tid & 63, l15 = lane & 15, l4 = lane >> 4;

    const size_t hb  = (size_t)g * NSEQ;
    const size_t hbv = (size_t)g * 32;

    // cooperative K staging: [320 keys][32 d] -> LDS stride 36 (<=2-way, free)
    {
        const uint4* src = (const uint4*)(kh + hb * 32);
        #pragma unroll
        for (int it = 0; it < 5; ++it) {
            int idx = it * 256 + tid;            // 0..1279
            int key = idx >> 2, part = idx & 3;
            uint4 u = src[idx];
            *(uint4*)&Klds[key * 36 + part * 8] = u;
        }
    }

    const int qrow = qblk * 64 + wave * 16;
    const int qb16 = qblk * 4 + wave;

    bf16x8 aQ = *(const bf16x8*)&qh[(hb + qrow + l15) * 32 + l4 * 8];
    const float* bsw = biasS + (size_t)(h * 20 + qb16) * 20 * 256 + lane * 4;
    const int*   mp  = maskT + b * NSEQ + l15;

    // all 20 bias C-operands issued together (independent dwordx4 loads)
    f32x4 s[20];
    #pragma unroll
    for (int t = 0; t < 20; ++t) s[t] = *(const f32x4*)&bsw[t * 256];

    __syncthreads();

    // S = Q K^T + bias (K-frags from LDS: short-latency, shared 4x)
    #pragma unroll
    for (int t = 0; t < 20; ++t) {
        bf16x8 bK = *(const bf16x8*)&Klds[(t * 16 + l15) * 36 + l4 * 8];
        s[t] = __builtin_amdgcn_mfma_f32_16x16x32_bf16(aQ, bK, s[t], 0, 0, 0);
    }

    // mask (key,b) -> exactly -1e9 (matches reference where-fill; fully-masked row -> uniform)
    #pragma unroll
    for (int t = 0; t < 20; ++t) {
        int m = mp[t * 16];
        #pragma unroll
        for (int r = 0; r < 4; ++r) s[t][r] = m ? s[t][r] : NEG_BIG;
    }

    // softmax over keys per q-row
    #pragma unroll
    for (int r = 0; r < 4; ++r) {
        float mx = -3.4e38f;
        #pragma unroll
        for (int t = 0; t < 20; ++t) mx = fmaxf(mx, s[t][r]);
        mx = fmaxf(mx, __shfl_xor(mx, 1));
        mx = fmaxf(mx, __shfl_xor(mx, 2));
        mx = fmaxf(mx, __shfl_xor(mx, 4));
        mx = fmaxf(mx, __shfl_xor(mx, 8));
        float l = 0.f;
        #pragma unroll
        for (int t = 0; t < 20; ++t) { float p = __expf(s[t][r] - mx); s[t][r] = p; l += p; }
        l += __shfl_xor(l, 1); l += __shfl_xor(l, 2); l += __shfl_xor(l, 4); l += __shfl_xor(l, 8);
        float wv = 1.f / l;
        #pragma unroll
        for (int t = 0; t < 20; ++t) s[t][r] *= wv;
    }

    // PV: P streamed through per-wave LDS dbuf (32 keys/chunk); V from global (L2-shared)
    unsigned short* pb[2] = { Pb[wave][0], Pb[wave][1] };
    #pragma unroll
    for (int tt = 0; tt < 2; ++tt)
        #pragma unroll
        for (int r = 0; r < 4; ++r)
            pb[0][(l4 * 4 + r) * 36 + tt * 16 + l15] = f2bf(s[tt][r]);

    f32x4 acc[2];
    { f32x4 z = {0.f,0.f,0.f,0.f}; acc[0] = z; acc[1] = z; }
    #pragma unroll
    for (int kc = 0; kc < 10; ++kc) {
        bf16x8 aW = *(const bf16x8*)&pb[kc & 1][l15 * 36 + l4 * 8];
        if (kc < 9) {
            unsigned short* nxt = pb[(kc + 1) & 1];
            #pragma unroll
            for (int tt = 0; tt < 2; ++tt)
                #pragma unroll
                for (int r = 0; r < 4; ++r)
                    nxt[(l4 * 4 + r) * 36 + tt * 16 + l15] = f2bf(s[2 * kc + 2 + tt][r]);
        }
        #pragma unroll
        for (int ns = 0; ns < 2; ++ns) {
            bf16x8 bV = *(const bf16x8*)&vT[(hbv + ns * 16 + l15) * NSEQ + kc * 32 + l4 * 8];
            acc[ns] = __builtin_amdgcn_mfma_f32_16x16x32_bf16(aW, bV, acc[ns], 0, 0, 0);
        }
    }

    // epilogue: normalize done, * gate -> bf16, head-major (block-contiguous lines)
    #pragma unroll
    for (int ns = 0; ns < 2; ++ns)
        #pragma unroll
        for (int r = 0; r < 4; ++r) {
            int q   = qrow + l4 * 4 + r;
            int col = ns * 16 + l15;
            float gv = bf2f(gh[(hb + q) * 32 + col]);
            waG[(hb + q) * 32 + col] = f2bf(acc[ns][r] * gv);
        }
}

// ---------------- k3: output projection ----------------
// A = wa*gate in head-major layout [(b,h),q,d]; logical A row=(b,q), col=h*32+d.
__global__ __launch_bounds__(256, 4) void out_proj_kernel(
    const unsigned short* __restrict__ waG, const unsigned short* __restrict__ woutb,
    float* __restrict__ out)
{
    __shared__ __align__(16) unsigned short A_lds[64 * 136];
    __shared__ __align__(16) unsigned short B_lds[128 * 136];
    const int tid  = threadIdx.x;
    const int row0 = blockIdx.x * 64;
    const int bidx = row0 / NSEQ;           // 320%64==0
    const int qoff = row0 % NSEQ;

    #pragma unroll
    for (int it = 0; it < 4; ++it) {
        int f = it * 256 + tid;
        int row = f >> 4, c16 = f & 15;
        int hh = c16 >> 2, d0 = (c16 & 3) * 8;
        uint4 u = *(const uint4*)&waG[((size_t)(bidx * 4 + hh) * NSEQ + (qoff + row)) * 32 + d0];
        *(uint4*)&A_lds[row * 136 + c16 * 8] = u;
    }
    #pragma unroll
    for (int it = 0; it < 8; ++it) {
        int f = it * 256 + tid;
        int row = f >> 4, c16 = f & 15;
        uint4 u = *(const uint4*)&woutb[f * 8];
        *(uint4*)&B_lds[row * 136 + c16 * 8] = u;
    }
    __syncthreads();

    const int wave = tid >> 6, lane = tid & 63, l15 = lane & 15, l4 = lane >> 4;
    bf16x8 afrag[4];
    #pragma unroll
    for (int kc = 0; kc < 4; ++kc)
        afrag[kc] = *(const bf16x8*)&A_lds[(wave * 16 + l15) * 136 + kc * 32 + l4 * 8];
    f32x4 acc[8];
    #pragma unroll
    for (int ns = 0; ns < 8; ++ns) { f32x4 z = {0.f,0.f,0.f,0.f}; acc[ns] = z; }
    #pragma unroll
    for (int ns = 0; ns < 8; ++ns)
        #pragma unroll
        for (int kc = 0; kc < 4; ++kc) {
            bf16x8 bfrag = *(const bf16x8*)&B_lds[(ns * 16 + l15) * 136 + kc * 32 + l4 * 8];
            acc[ns] = __builtin_amdgcn_mfma_f32_16x16x32_bf16(afrag[kc], bfrag, acc[ns], 0, 0, 0);
        }
    #pragma unroll
    for (int ns = 0; ns < 8; ++ns)
        #pragma unroll
        for (int reg = 0; reg < 4; ++reg) {
            int r = row0 + wave * 16 + l4 * 4 + reg;
            out[(size_t)r * 128 + ns * 16 + l15] = acc[ns][reg];
        }
}

// ---------------- launch ----------------
extern "C" void kernel_launch(void* const* d_in, const int* in_sizes, int n_in,
                              void* d_out, int out_size, void* d_ws, size_t ws_size,
                              hipStream_t stream)
{
    (void)in_sizes; (void)n_in; (void)out_size;
    const float* act  = (const float*)d_in[0];
    const int*   pmsk = (const int*)d_in[1];
    const float* gam  = (const float*)d_in[2];
    const float* bet  = (const float*)d_in[3];
    const float* wpb  = (const float*)d_in[4];
    const float* wq   = (const float*)d_in[5];
    const float* wk   = (const float*)d_in[6];
    const float* wv   = (const float*)d_in[7];
    const float* wg   = (const float*)d_in[8];
    const float* wo   = (const float*)d_in[9];
    float* out = (float*)d_out;

    char* ws = (char*)d_ws;
    unsigned short* wcat  = (unsigned short*)(ws + 0);          //   147456 B
    unsigned short* woutb = (unsigned short*)(ws + 147456);     //    32768 B
    int*            maskT = (int*)           (ws + 180224);     //   409600 B
    float*          biasS = (float*)         (ws + 589824);     //  1638400 B (swizzled)
    unsigned short* qh    = (unsigned short*)(ws + 2228224);    // 26214400 B
    unsigned short* kh    = (unsigned short*)(ws + 28442624);
    unsigned short* vT    = (unsigned short*)(ws + 54657024);
    unsigned short* gh    = (unsigned short*)(ws + 80871424);
    unsigned short* waG   = (unsigned short*)(ws + 107085824);  // head-major, ends 133300224
    if (ws_size < 133300224ull) {
        fprintf(stderr, "kernel_launch: ws too small (%zu < 133300224)\n", ws_size);
        return;
    }

    prep_kernel    <<<752,  256, 0, stream>>>(wq, wk, wv, wg, wpb, wo, pmsk, wcat, woutb, maskT);
    ln_proj_kernel <<<1600, 256, 0, stream>>>(act, gam, bet, wcat, qh, kh, vT, gh, biasS);
    attn_kernel    <<<6400, 256, 0, stream>>>(qh, kh, vT, gh, biasS, maskT, waG);
    out_proj_kernel<<<1600, 256, 0, stream>>>(waG, woutb, out);
}